// Round 5
// baseline (291.192 us; speedup 1.0000x reference)
//
#include <hip/hip_runtime.h>

using u16 = unsigned short;
using u32 = unsigned int;
using s16x8 = __attribute__((ext_vector_type(8))) short;
using bf16x8 = __attribute__((ext_vector_type(8))) __bf16;
using f32x4 = __attribute__((ext_vector_type(4))) float;

__device__ inline u16 f2bf(float f) {
  u32 u = __float_as_uint(f);
  u = (u + 0x7FFFu + ((u >> 16) & 1u)) >> 16;
  return (u16)u;
}

__device__ inline f32x4 mfma16(s16x8 a, s16x8 b, f32x4 c) {
  return __builtin_amdgcn_mfma_f32_16x16x32_bf16(
      __builtin_bit_cast(bf16x8, a), __builtin_bit_cast(bf16x8, b), c, 0, 0, 0);
}

// async global->LDS, 16B/lane; LDS dest = wave-uniform base + lane*16
__device__ inline void load_lds16(const void* g, void* l) {
  __builtin_amdgcn_global_load_lds(
      (const __attribute__((address_space(1))) void*)g,
      (__attribute__((address_space(3))) void*)l, 16, 0, 0);
}

// ---------------------------------------------------------------------------
// x1 + x2 casts in one launch (blockIdx.y selects)
// ---------------------------------------------------------------------------
__global__ __launch_bounds__(256) void cast_x12(
    const float* __restrict__ x1, const float* __restrict__ x2,
    u16* __restrict__ o1, u16* __restrict__ o2) {
  const float* in = blockIdx.y ? x2 : x1;
  u16* out = blockIdx.y ? o2 : o1;
  int i = (blockIdx.x * 256 + threadIdx.x) * 4;
  float4 f = *(const float4*)(in + i);
  ushort4 o;
  o.x = f2bf(f.x); o.y = f2bf(f.y); o.z = f2bf(f.z); o.w = f2bf(f.w);
  *(ushort4*)(out + i) = o;
}

// weights cast (y=0..2) + lbuf zero (y=3, first 64 blocks)
__global__ __launch_bounds__(256) void cast_w3z(
    const float* __restrict__ a, const float* __restrict__ b,
    const float* __restrict__ c, u16* __restrict__ oa, u16* __restrict__ ob,
    u16* __restrict__ oc, float* __restrict__ lbuf) {
  if (blockIdx.y == 3) {
    if (blockIdx.x < 64) lbuf[blockIdx.x * 256 + threadIdx.x] = 0.0f;
    return;
  }
  const float* in = blockIdx.y == 0 ? a : (blockIdx.y == 1 ? b : c);
  u16* out = blockIdx.y == 0 ? oa : (blockIdx.y == 1 ? ob : oc);
  int i = (blockIdx.x * 256 + threadIdx.x) * 4;
  float4 f = *(const float4*)(in + i);
  ushort4 o;
  o.x = f2bf(f.x); o.y = f2bf(f.y); o.z = f2bf(f.z); o.w = f2bf(f.w);
  *(ushort4*)(out + i) = o;
}

// ---------------------------------------------------------------------------
// bf16 GEMM, C[m,n] = sum_k A[m,k]*B[n,k]  (both operands K-contiguous).
// 128x128 tile, BK=64, 4 waves (2x2), 2x(4x4) 16x16x32 MFMAs per iter.
// LDS granule XOR swizzle (slot = g ^ (row&7)) applied via staging SOURCE
// address, keeping the wave-uniform-base global_load_lds contract (0 bank
// conflicts measured r3).
// EPI 0: bf16 out = acc + bias[n]                          (q projection)
// EPI 4: fused k/v projection: n0<512 -> kb (+bias); n0>=512 -> vT[b][d][s]
//        transposed via LDS repack (+bias2), coalesced 256B-run stores
// EPI 2: bf16 out = exp(acc*scale), atomic row sums -> lsum     (scores)
// EPI 3: fp32 out = acc * rcp(lsum[row])                        (PV)
// ---------------------------------------------------------------------------
template <int EPI>
__global__ __launch_bounds__(256) void gemm64(
    const u16* __restrict__ A, const u16* __restrict__ B,
    const u16* __restrict__ B2, void* __restrict__ C, void* __restrict__ C2,
    const float* __restrict__ bias, const float* __restrict__ bias2,
    float* __restrict__ lsum, float scale,
    int M, int N, int K, long sA, long sB, long sC) {
  const int bz = blockIdx.z;
  const int m0 = blockIdx.y * 128;
  const int n0 = blockIdx.x * 128;
  const u16* Ab = A + (size_t)bz * sA;
  const u16* Bsel = (EPI == 4 && n0 >= 512) ? B2 : B;
  const int nb = (EPI == 4 && n0 >= 512) ? n0 - 512 : n0;
  const u16* Bb = Bsel + (size_t)bz * sB;
  const int tid = threadIdx.x;
  const int lane = tid & 63;
  const int wave = tid >> 6;
  const int wm = (wave >> 1) * 64;
  const int wn = (wave & 1) * 64;

  __shared__ u16 SM[128 * 64 * 2];
  u16* As = SM;
  u16* Bs = SM + 128 * 64;

  // staging: 16 chunks/operand of 1024B (8 rows x 64 cols); wave w: 4w..4w+3
  const int sr = lane >> 3;        // row within 8-row chunk
  const int gd = (lane & 7) ^ sr;  // swizzled source granule (16B units)
  const int ch0 = wave * 4;

  f32x4 acc[4][4];
#pragma unroll
  for (int i = 0; i < 4; ++i)
#pragma unroll
    for (int j = 0; j < 4; ++j) acc[i][j] = 0.0f;

  const int fr = lane & 15;
  const int fg = lane >> 4;  // 0..3

  for (int k0 = 0; k0 < K; k0 += 64) {
#pragma unroll
    for (int it = 0; it < 4; ++it) {
      const int ch = ch0 + it;
      const int row = ch * 8 + sr;
      load_lds16(Ab + (size_t)(m0 + row) * K + k0 + gd * 8, &As[ch * 512]);
      load_lds16(Bb + (size_t)(nb + row) * K + k0 + gd * 8, &Bs[ch * 512]);
    }
    __syncthreads();
#pragma unroll
    for (int s = 0; s < 2; ++s) {
      const int slot = ((s * 4 + fg) ^ (fr & 7)) * 8;
      s16x8 af[4], bfr[4];
#pragma unroll
      for (int i = 0; i < 4; ++i) {
        af[i]  = *(const s16x8*)&As[(wm + i * 16 + fr) * 64 + slot];
        bfr[i] = *(const s16x8*)&Bs[(wn + i * 16 + fr) * 64 + slot];
      }
#pragma unroll
      for (int mi = 0; mi < 4; ++mi)
#pragma unroll
        for (int ni = 0; ni < 4; ++ni)
          acc[mi][ni] = mfma16(af[mi], bfr[ni], acc[mi][ni]);
    }
    __syncthreads();
  }

  // C/D layout: col = lane&15, row = (lane>>4)*4 + i
  const int er = fg * 4;
  const int ec = fr;

  if (EPI == 0) {
    u16* Cb = (u16*)C;
#pragma unroll
    for (int mi = 0; mi < 4; ++mi)
#pragma unroll
      for (int ni = 0; ni < 4; ++ni) {
        const int col = n0 + wn + ni * 16 + ec;
        const float badd = bias[col];
#pragma unroll
        for (int i = 0; i < 4; ++i) {
          const int row = m0 + wm + mi * 16 + er + i;
          Cb[(size_t)row * N + col] = f2bf(acc[mi][ni][i] + badd);
        }
      }
  } else if (EPI == 4) {
    if (n0 < 512) {
      // k-projection half: plain row-major store, stride 512
      u16* Cb = (u16*)C;
#pragma unroll
      for (int mi = 0; mi < 4; ++mi)
#pragma unroll
        for (int ni = 0; ni < 4; ++ni) {
          const int col = n0 + wn + ni * 16 + ec;
          const float badd = bias[col];
#pragma unroll
          for (int i = 0; i < 4; ++i) {
            const int row = m0 + wm + mi * 16 + er + i;
            Cb[(size_t)row * 512 + col] = f2bf(acc[mi][ni][i] + badd);
          }
        }
    } else {
      // v-projection half: transpose via LDS, store vT[b][d][s].
      // Tb[c][r]: c = local d-col (0..63 per pass), r = token row (0..127),
      // row stride 136 u16 (272 B, 16B-aligned).
      u16* Tb = SM;  // 64*136 u16 = 17408 B, aliases staging (dead now)
      const int batch = m0 >> 11;
      const int srow = m0 & 2047;
      u16* Cv = (u16*)C2 + (size_t)batch * (512 * 2048);
#pragma unroll
      for (int h = 0; h < 2; ++h) {
        if ((wn >> 6) == h) {
#pragma unroll
          for (int mi = 0; mi < 4; ++mi)
#pragma unroll
            for (int ni = 0; ni < 4; ++ni) {
              const int c = ni * 16 + ec;
              const float badd = bias2[n0 - 512 + wn + c];
#pragma unroll
              for (int i = 0; i < 4; ++i) {
                const int r = wm + mi * 16 + er + i;
                Tb[c * 136 + r] = f2bf(acc[mi][ni][i] + badd);
              }
            }
        }
        __syncthreads();
        // readback: thread -> d-row tid>>2, s-chunk (tid&3)*32, 32 u16 each
        // (four uint4 = 4 x 8 u16; fixed from r4 where 2 x j*16 left gaps)
        const int d = tid >> 2;
        const int sc = (tid & 3) * 32;
        const int dglob = n0 - 512 + 64 * h + d;
#pragma unroll
        for (int j = 0; j < 4; ++j) {
          uint4 v = *(const uint4*)&Tb[d * 136 + sc + j * 8];
          *(uint4*)&Cv[(size_t)dglob * 2048 + srow + sc + j * 8] = v;
        }
        __syncthreads();
      }
    }
  } else if (EPI == 2) {
    u16* Cb = (u16*)C + (size_t)bz * sC;
#pragma unroll
    for (int mi = 0; mi < 4; ++mi) {
      float rs[4] = {0.0f, 0.0f, 0.0f, 0.0f};
#pragma unroll
      for (int ni = 0; ni < 4; ++ni) {
        const int col = n0 + wn + ni * 16 + ec;
#pragma unroll
        for (int i = 0; i < 4; ++i) {
          const float p = __expf(acc[mi][ni][i] * scale);
          rs[i] += p;
          Cb[(size_t)(m0 + wm + mi * 16 + er + i) * N + col] = f2bf(p);
        }
      }
#pragma unroll
      for (int i = 0; i < 4; ++i) {
        rs[i] += __shfl_xor(rs[i], 1);
        rs[i] += __shfl_xor(rs[i], 2);
        rs[i] += __shfl_xor(rs[i], 4);
        rs[i] += __shfl_xor(rs[i], 8);
      }
      if (ec == 0) {
#pragma unroll
        for (int i = 0; i < 4; ++i)
          atomicAdd(&lsum[(size_t)bz * M + m0 + wm + mi * 16 + er + i], rs[i]);
      }
    }
  } else {  // EPI == 3: PV, normalize by rcp(l)
    float* Cb = (float*)C + (size_t)bz * sC;
#pragma unroll
    for (int mi = 0; mi < 4; ++mi)
#pragma unroll
      for (int i = 0; i < 4; ++i) {
        const int row = m0 + wm + mi * 16 + er + i;
        const float li = __builtin_amdgcn_rcpf(lsum[(size_t)bz * M + row]);
#pragma unroll
        for (int ni = 0; ni < 4; ++ni) {
          const int col = n0 + wn + ni * 16 + ec;
          Cb[(size_t)row * N + col] = acc[mi][ni][i] * li;
        }
      }
  }
}

// ---------------------------------------------------------------------------
extern "C" void kernel_launch(void* const* d_in, const int* in_sizes, int n_in,
                              void* d_out, int out_size, void* d_ws, size_t ws_size,
                              hipStream_t stream) {
  constexpr int B = 8, S = 2048, D = 512;
  constexpr size_t MS = (size_t)B * S;  // 16384 token rows

  const float* x1 = (const float*)d_in[0];
  const float* x2 = (const float*)d_in[1];
  const float* Wq = (const float*)d_in[2];
  const float* bq = (const float*)d_in[3];
  const float* Wk = (const float*)d_in[4];
  const float* bk = (const float*)d_in[5];
  const float* Wv = (const float*)d_in[6];
  const float* bv = (const float*)d_in[7];
  float* out = (float*)d_out;

  // workspace (u16 elements unless noted)
  u16* x1b = (u16*)d_ws;              // MS*D
  u16* x2b = x1b + MS * D;            // MS*D
  u16* Wqb = x2b + MS * D;            // D*D
  u16* Wkb = Wqb + (size_t)D * D;
  u16* Wvb = Wkb + (size_t)D * D;
  u16* qb  = Wvb + (size_t)D * D;     // MS*D
  u16* kb  = qb + MS * D;             // MS*D
  u16* vTb = kb + MS * D;             // MS*D   [B][D][S]
  u16* Sc  = vTb + MS * D;            // B*S*S  (67 MB)
  float* lbuf = (float*)(Sc + (size_t)B * S * S);  // B*S fp32 row sums

  dim3 blk(256);

  // casts + lbuf zero (2 launches)
  cast_x12<<<dim3((MS * D) / 1024, 2), blk, 0, stream>>>(x1, x2, x1b, x2b);
  cast_w3z<<<dim3((D * D) / 1024, 4), blk, 0, stream>>>(
      Wq, Wk, Wv, Wqb, Wkb, Wvb, lbuf);

  // q projection: M=16384, N=512, K=512
  gemm64<0><<<dim3(4, 128, 1), blk, 0, stream>>>(
      x1b, Wqb, nullptr, qb, nullptr, bq, nullptr, nullptr, 0.0f,
      16384, 512, 512, 0, 0, 0);

  // fused k+v projection: N=1024 (k half -> kb, v half -> vT transposed)
  gemm64<4><<<dim3(8, 128, 1), blk, 0, stream>>>(
      x2b, Wkb, Wvb, kb, vTb, bk, bv, nullptr, 0.0f,
      16384, 512, 512, 0, 0, 0);

  // scores: per batch M=2048, N=2048, K=512; epilogue exp(s/D) + row sums
  gemm64<2><<<dim3(16, 16, B), blk, 0, stream>>>(
      qb, kb, nullptr, Sc, nullptr, nullptr, nullptr, lbuf, 1.0f / (float)D,
      2048, 2048, 512, (long)S * D, (long)S * D, (long)S * S);

  // PV: per batch M=2048, N=512, K=2048; epilogue scale by rcp(l), fp32 out
  gemm64<3><<<dim3(4, 16, B), blk, 0, stream>>>(
      Sc, vTb, nullptr, out, nullptr, nullptr, nullptr, lbuf, 0.0f,
      2048, 512, 2048, (long)S * S, (long)D * S, (long)S * D);
}

// Round 7
// 259.293 us; speedup vs baseline: 1.1230x; 1.1230x over previous
//
#include <hip/hip_runtime.h>

using u8  = unsigned char;
using u16 = unsigned short;
using u32 = unsigned int;
using s16x8 = __attribute__((ext_vector_type(8))) short;
using bf16x8 = __attribute__((ext_vector_type(8))) __bf16;
using f32x4 = __attribute__((ext_vector_type(4))) float;
using i32x4 = __attribute__((ext_vector_type(4))) int;
using i32x8 = __attribute__((ext_vector_type(8))) int;

__device__ inline u16 f2bf(float f) {
  u32 u = __float_as_uint(f);
  u = (u + 0x7FFFu + ((u >> 16) & 1u)) >> 16;
  return (u16)u;
}

// fp8 e4m3 (OCP) convert via HW pack instruction; take low byte
__device__ inline u8 f2fp8(float f) {
  return (u8)(__builtin_amdgcn_cvt_pk_fp8_f32(f, f, 0, false) & 0xFF);
}

__device__ inline f32x4 mfma16(s16x8 a, s16x8 b, f32x4 c) {
  return __builtin_amdgcn_mfma_f32_16x16x32_bf16(
      __builtin_bit_cast(bf16x8, a), __builtin_bit_cast(bf16x8, b), c, 0, 0, 0);
}

// MX fp8 MFMA, K=128, unit scales (e8m0 127 = 2^0): plain fp8 GEMM @2x bf16 rate
__device__ inline f32x4 mfma_fp8(i32x8 a, i32x8 b, f32x4 c) {
  return __builtin_amdgcn_mfma_scale_f32_16x16x128_f8f6f4(
      a, b, c, 0 /*A=fp8*/, 0 /*B=fp8*/, 0, 127, 0, 127);
}

// async global->LDS, 16B/lane; LDS dest = wave-uniform base + lane*16
__device__ inline void load_lds16(const void* g, void* l) {
  __builtin_amdgcn_global_load_lds(
      (const __attribute__((address_space(1))) void*)g,
      (__attribute__((address_space(3))) void*)l, 16, 0, 0);
}

// ---------------------------------------------------------------------------
__global__ __launch_bounds__(256) void cast_x12(
    const float* __restrict__ x1, const float* __restrict__ x2,
    u16* __restrict__ o1, u16* __restrict__ o2) {
  const float* in = blockIdx.y ? x2 : x1;
  u16* out = blockIdx.y ? o2 : o1;
  int i = (blockIdx.x * 256 + threadIdx.x) * 4;
  float4 f = *(const float4*)(in + i);
  ushort4 o;
  o.x = f2bf(f.x); o.y = f2bf(f.y); o.z = f2bf(f.z); o.w = f2bf(f.w);
  *(ushort4*)(out + i) = o;
}

// weights cast (y=0..2) + lbuf zero (y=3, first 64 blocks)
__global__ __launch_bounds__(256) void cast_w3z(
    const float* __restrict__ a, const float* __restrict__ b,
    const float* __restrict__ c, u16* __restrict__ oa, u16* __restrict__ ob,
    u16* __restrict__ oc, float* __restrict__ lbuf) {
  if (blockIdx.y == 3) {
    if (blockIdx.x < 64) lbuf[blockIdx.x * 256 + threadIdx.x] = 0.0f;
    return;
  }
  const float* in = blockIdx.y == 0 ? a : (blockIdx.y == 1 ? b : c);
  u16* out = blockIdx.y == 0 ? oa : (blockIdx.y == 1 ? ob : oc);
  int i = (blockIdx.x * 256 + threadIdx.x) * 4;
  float4 f = *(const float4*)(in + i);
  ushort4 o;
  o.x = f2bf(f.x); o.y = f2bf(f.y); o.z = f2bf(f.z); o.w = f2bf(f.w);
  *(ushort4*)(out + i) = o;
}

// ---------------------------------------------------------------------------
// bf16 GEMM, C[m,n] = sum_k A[m,k]*B[n,k]  (operands K-contiguous).
// 128x128 tile, BK=64, 4 waves, XOR granule swizzle (0 bank conflicts, r3).
// EPI 0: q projection -> fp8 row-major [16384][512] (+bias)
// EPI 4: fused k/v: n0<512 -> kb fp8 row-major (+bias);
//        n0>=512 -> vT[b][d][s] bf16 via LDS repack (+bias2)
// EPI 3: PV: fp32 out = acc * rcp(lsum[row])
// ---------------------------------------------------------------------------
template <int EPI>
__global__ __launch_bounds__(256) void gemm64(
    const u16* __restrict__ A, const u16* __restrict__ B,
    const u16* __restrict__ B2, void* __restrict__ C, void* __restrict__ C2,
    const float* __restrict__ bias, const float* __restrict__ bias2,
    const float* __restrict__ lsum,
    int M, int N, int K, long sA, long sB, long sC) {
  const int bz = blockIdx.z;
  const int m0 = blockIdx.y * 128;
  const int n0 = blockIdx.x * 128;
  const u16* Ab = A + (size_t)bz * sA;
  const u16* Bsel = (EPI == 4 && n0 >= 512) ? B2 : B;
  const int nb = (EPI == 4 && n0 >= 512) ? n0 - 512 : n0;
  const u16* Bb = Bsel + (size_t)bz * sB;
  const int tid = threadIdx.x;
  const int lane = tid & 63;
  const int wave = tid >> 6;
  const int wm = (wave >> 1) * 64;
  const int wn = (wave & 1) * 64;

  __shared__ u16 SM[128 * 64 * 2];
  u16* As = SM;
  u16* Bs = SM + 128 * 64;

  const int sr = lane >> 3;        // row within 8-row chunk
  const int gd = (lane & 7) ^ sr;  // swizzled source granule (16B units)
  const int ch0 = wave * 4;

  f32x4 acc[4][4];
#pragma unroll
  for (int i = 0; i < 4; ++i)
#pragma unroll
    for (int j = 0; j < 4; ++j) acc[i][j] = 0.0f;

  const int fr = lane & 15;
  const int fg = lane >> 4;  // 0..3

  for (int k0 = 0; k0 < K; k0 += 64) {
#pragma unroll
    for (int it = 0; it < 4; ++it) {
      const int ch = ch0 + it;
      const int row = ch * 8 + sr;
      load_lds16(Ab + (size_t)(m0 + row) * K + k0 + gd * 8, &As[ch * 512]);
      load_lds16(Bb + (size_t)(nb + row) * K + k0 + gd * 8, &Bs[ch * 512]);
    }
    __syncthreads();
#pragma unroll
    for (int s = 0; s < 2; ++s) {
      const int slot = ((s * 4 + fg) ^ (fr & 7)) * 8;
      s16x8 af[4], bfr[4];
#pragma unroll
      for (int i = 0; i < 4; ++i) {
        af[i]  = *(const s16x8*)&As[(wm + i * 16 + fr) * 64 + slot];
        bfr[i] = *(const s16x8*)&Bs[(wn + i * 16 + fr) * 64 + slot];
      }
#pragma unroll
      for (int mi = 0; mi < 4; ++mi)
#pragma unroll
        for (int ni = 0; ni < 4; ++ni)
          acc[mi][ni] = mfma16(af[mi], bfr[ni], acc[mi][ni]);
    }
    __syncthreads();
  }

  // C/D layout: col = lane&15, row = (lane>>4)*4 + i
  const int er = fg * 4;
  const int ec = fr;

  if (EPI == 0) {
    u8* Cb = (u8*)C;
#pragma unroll
    for (int mi = 0; mi < 4; ++mi)
#pragma unroll
      for (int ni = 0; ni < 4; ++ni) {
        const int col = n0 + wn + ni * 16 + ec;
        const float badd = bias[col];
#pragma unroll
        for (int i = 0; i < 4; ++i) {
          const int row = m0 + wm + mi * 16 + er + i;
          Cb[(size_t)row * N + col] = f2fp8(acc[mi][ni][i] + badd);
        }
      }
  } else if (EPI == 4) {
    if (n0 < 512) {
      // k-projection half: fp8 row-major, stride 512
      u8* Cb = (u8*)C;
#pragma unroll
      for (int mi = 0; mi < 4; ++mi)
#pragma unroll
        for (int ni = 0; ni < 4; ++ni) {
          const int col = n0 + wn + ni * 16 + ec;
          const float badd = bias[col];
#pragma unroll
          for (int i = 0; i < 4; ++i) {
            const int row = m0 + wm + mi * 16 + er + i;
            Cb[(size_t)row * 512 + col] = f2fp8(acc[mi][ni][i] + badd);
          }
        }
    } else {
      // v half: transpose via LDS repack, bf16 out. Tb[c][r], stride 136 u16.
      u16* Tb = SM;  // 64*136 u16 = 17408 B, aliases dead staging
      const int batch = m0 >> 11;
      const int srow = m0 & 2047;
      u16* Cv = (u16*)C2 + (size_t)batch * (512 * 2048);
#pragma unroll
      for (int h = 0; h < 2; ++h) {
        if ((wn >> 6) == h) {
#pragma unroll
          for (int mi = 0; mi < 4; ++mi)
#pragma unroll
            for (int ni = 0; ni < 4; ++ni) {
              const int c = ni * 16 + ec;
              const float badd = bias2[n0 - 512 + wn + c];
#pragma unroll
              for (int i = 0; i < 4; ++i) {
                const int r = wm + mi * 16 + er + i;
                Tb[c * 136 + r] = f2bf(acc[mi][ni][i] + badd);
              }
            }
        }
        __syncthreads();
        // readback: thread -> d-row tid>>2, s-chunk (tid&3)*32, 32 u16 each
        const int d = tid >> 2;
        const int sc = (tid & 3) * 32;
        const int dglob = n0 - 512 + 64 * h + d;
#pragma unroll
        for (int j = 0; j < 4; ++j) {
          uint4 v = *(const uint4*)&Tb[d * 136 + sc + j * 8];
          *(uint4*)&Cv[(size_t)dglob * 2048 + srow + sc + j * 8] = v;
        }
        __syncthreads();
      }
    }
  } else {  // EPI == 3: PV, normalize by rcp(l)
    float* Cb = (float*)C + (size_t)bz * sC;
#pragma unroll
    for (int mi = 0; mi < 4; ++mi)
#pragma unroll
      for (int i = 0; i < 4; ++i) {
        const int row = m0 + wm + mi * 16 + er + i;
        const float li = __builtin_amdgcn_rcpf(lsum[(size_t)bz * M + row]);
#pragma unroll
        for (int ni = 0; ni < 4; ++ni) {
          const int col = n0 + wn + ni * 16 + ec;
          Cb[(size_t)row * N + col] = acc[mi][ni][i] * li;
        }
      }
  }
}

// ---------------------------------------------------------------------------
// fp8 scores GEMM via MX(unit-scale) mfma 16x16x128, BK=128, 32 KB LDS.
// P = exp(acc*scale) -> bf16 out + atomic row sums -> lsum.
// (fp8 machinery validated r6: error there matched pure quantization noise.)
// ---------------------------------------------------------------------------
__global__ __launch_bounds__(256) void gemm_fp8_scores(
    const u8* __restrict__ A, const u8* __restrict__ B, u16* __restrict__ C,
    float* __restrict__ lsum, float scale,
    int M, int N, int K, long sA, long sB, long sC) {
  const int bz = blockIdx.z;
  const int m0 = blockIdx.y * 128;
  const int n0 = blockIdx.x * 128;
  const u8* Ab = A + (size_t)bz * sA;
  const u8* Bb = B + (size_t)bz * sB;
  const int tid = threadIdx.x;
  const int lane = tid & 63;
  const int wave = tid >> 6;
  const int wm = (wave >> 1) * 64;
  const int wn = (wave & 1) * 64;

  __shared__ u8 As8[128 * 128];
  __shared__ u8 Bs8[128 * 128];

  const int sr = lane >> 3;         // row within 8-row chunk
  const int gd = (lane & 7) ^ sr;   // swizzled source granule (16B units)
  const int ch0 = wave * 4;

  f32x4 acc[4][4];
#pragma unroll
  for (int i = 0; i < 4; ++i)
#pragma unroll
    for (int j = 0; j < 4; ++j) acc[i][j] = 0.0f;

  const int fr = lane & 15;
  const int fg = lane >> 4;         // 0..3 -> k-bytes [fg*32, fg*32+32)
  const int r7 = fr & 7;
  const int s0 = (2 * fg) ^ r7;     // LDS slot of k-lo granule
  const int s1 = s0 ^ 1;            // k-hi granule

  for (int k0 = 0; k0 < K; k0 += 128) {
#pragma unroll
    for (int it = 0; it < 4; ++it) {
      const int ch = ch0 + it;
      const int row = ch * 8 + sr;
      load_lds16(Ab + (size_t)(m0 + row) * K + k0 + gd * 16, &As8[ch * 1024]);
      load_lds16(Bb + (size_t)(n0 + row) * K + k0 + gd * 16, &Bs8[ch * 1024]);
    }
    __syncthreads();
    i32x8 af[4], bfv[4];
#pragma unroll
    for (int i = 0; i < 4; ++i) {
      const u8* pa = &As8[(wm + i * 16 + fr) * 128];
      i32x4 alo = *(const i32x4*)(pa + s0 * 16);
      i32x4 ahi = *(const i32x4*)(pa + s1 * 16);
      af[i][0] = alo[0]; af[i][1] = alo[1]; af[i][2] = alo[2]; af[i][3] = alo[3];
      af[i][4] = ahi[0]; af[i][5] = ahi[1]; af[i][6] = ahi[2]; af[i][7] = ahi[3];
      const u8* pb = &Bs8[(wn + i * 16 + fr) * 128];
      i32x4 blo = *(const i32x4*)(pb + s0 * 16);
      i32x4 bhi = *(const i32x4*)(pb + s1 * 16);
      bfv[i][0] = blo[0]; bfv[i][1] = blo[1]; bfv[i][2] = blo[2]; bfv[i][3] = blo[3];
      bfv[i][4] = bhi[0]; bfv[i][5] = bhi[1]; bfv[i][6] = bhi[2]; bfv[i][7] = bhi[3];
    }
#pragma unroll
    for (int mi = 0; mi < 4; ++mi)
#pragma unroll
      for (int ni = 0; ni < 4; ++ni)
        acc[mi][ni] = mfma_fp8(af[mi], bfv[ni], acc[mi][ni]);
    __syncthreads();
  }

  // C/D layout: col = lane&15, row = (lane>>4)*4 + i (shape-determined)
  const int er = fg * 4;
  const int ec = fr;
  u16* Cb = C + (size_t)bz * sC;
#pragma unroll
  for (int mi = 0; mi < 4; ++mi) {
    float rs[4] = {0.0f, 0.0f, 0.0f, 0.0f};
#pragma unroll
    for (int ni = 0; ni < 4; ++ni) {
      const int col = n0 + wn + ni * 16 + ec;
#pragma unroll
      for (int i = 0; i < 4; ++i) {
        const float p = __expf(acc[mi][ni][i] * scale);
        rs[i] += p;
        Cb[(size_t)(m0 + wm + mi * 16 + er + i) * N + col] = f2bf(p);
      }
    }
#pragma unroll
    for (int i = 0; i < 4; ++i) {
      rs[i] += __shfl_xor(rs[i], 1);
      rs[i] += __shfl_xor(rs[i], 2);
      rs[i] += __shfl_xor(rs[i], 4);
      rs[i] += __shfl_xor(rs[i], 8);
    }
    if (ec == 0) {
#pragma unroll
      for (int i = 0; i < 4; ++i)
        atomicAdd(&lsum[(size_t)bz * M + m0 + wm + mi * 16 + er + i], rs[i]);
    }
  }
}

// ---------------------------------------------------------------------------
extern "C" void kernel_launch(void* const* d_in, const int* in_sizes, int n_in,
                              void* d_out, int out_size, void* d_ws, size_t ws_size,
                              hipStream_t stream) {
  constexpr int B = 8, S = 2048, D = 512;
  constexpr size_t MS = (size_t)B * S;  // 16384 token rows

  const float* x1 = (const float*)d_in[0];
  const float* x2 = (const float*)d_in[1];
  const float* Wq = (const float*)d_in[2];
  const float* bq = (const float*)d_in[3];
  const float* Wk = (const float*)d_in[4];
  const float* bk = (const float*)d_in[5];
  const float* Wv = (const float*)d_in[6];
  const float* bv = (const float*)d_in[7];
  float* out = (float*)d_out;

  // workspace layout
  u16* x1b = (u16*)d_ws;              // MS*D bf16
  u16* x2b = x1b + MS * D;            // MS*D bf16
  u16* Wqb = x2b + MS * D;            // D*D bf16
  u16* Wkb = Wqb + (size_t)D * D;
  u16* Wvb = Wkb + (size_t)D * D;
  u16* vTb = Wvb + (size_t)D * D;     // MS*D bf16  [B][D][S]
  u16* Sc  = vTb + MS * D;            // B*S*S bf16 (67 MB)
  float* lbuf = (float*)(Sc + (size_t)B * S * S);  // B*S fp32 row sums
  u8* qb8 = (u8*)(lbuf + MS);         // MS*D fp8
  u8* kb8 = qb8 + MS * D;             // MS*D fp8

  dim3 blk(256);

  cast_x12<<<dim3((MS * D) / 1024, 2), blk, 0, stream>>>(x1, x2, x1b, x2b);
  cast_w3z<<<dim3((D * D) / 1024, 4), blk, 0, stream>>>(
      Wq, Wk, Wv, Wqb, Wkb, Wvb, lbuf);

  // q projection: M=16384, N=512, K=512 -> fp8
  gemm64<0><<<dim3(4, 128, 1), blk, 0, stream>>>(
      x1b, Wqb, nullptr, qb8, nullptr, bq, nullptr, nullptr,
      16384, 512, 512, 0, 0, 0);

  // fused k+v projection: N=1024 (k half -> kb8 fp8, v half -> vTb bf16)
  gemm64<4><<<dim3(8, 128, 1), blk, 0, stream>>>(
      x2b, Wkb, Wvb, kb8, vTb, bk, bv, nullptr,
      16384, 512, 512, 0, 0, 0);

  // scores: per batch M=2048, N=2048, K=512; fp8 MFMA; P bf16 + row sums
  gemm_fp8_scores<<<dim3(16, 16, B), blk, 0, stream>>>(
      qb8, kb8, Sc, lbuf, 1.0f / (float)D, 2048, 2048, 512,
      (long)S * D, (long)S * D, (long)S * S);

  // PV: per batch M=2048, N=512, K=2048; bf16; fp32 out * rcp(l)
  gemm64<3><<<dim3(4, 16, B), blk, 0, stream>>>(
      Sc, vTb, nullptr, out, nullptr, nullptr, nullptr, lbuf,
      2048, 512, 2048, (long)S * S, (long)D * S, (long)S * D);
}